// Round 11
// baseline (200.099 us; speedup 1.0000x reference)
//
#include <hip/hip_runtime.h>
#include <math.h>

#define B_    16
#define CIN_  128
#define COUT_ 256
#define H_    64
#define W_    64
#define HW_   4096

typedef __attribute__((ext_vector_type(8))) short short8v;
typedef __attribute__((ext_vector_type(4))) float f32x4;

// workspace layout (float offsets)
#define WS_GPX     0          // [16][64][128] = 131072
#define WS_RW      131072     // 64
#define WS_CP      131136     // conv gap partials [16][16][256] = 65536
#define WS_CA      196672     // 4096
#define WS_BNSCALE 208960     // 256
#define WS_BNSHIFT 209216     // 256
#define WS_SA      209472     // 65536
#define WS_WSA     275008     // 16384 bf16 = 8192 floats
#define WS_WCB_F   283200     // bf16 [16][9][256][128] = 4718592 bf16 = 2359296 floats
#define WS_XT_F    2642496    // bf16 [16][66][66][128] = 8921088 bf16 = 4460544 floats
#define WS_U_F     WS_XT_F    // bf16 [16][64][4096] (xt dead after conv)
#define WS_MIX_F   7103040    // bf16 [16][256][4096] = 16777216 bf16 = 8388608 floats

static __device__ __forceinline__ unsigned short f2bf(float f) {
    union { float f; unsigned int u; } v; v.f = f;
    unsigned int u = v.u;
    return (unsigned short)((u + 0x7FFFu + ((u >> 16) & 1u)) >> 16);  // RTNE
}
static __device__ __forceinline__ float bf2f(unsigned short h) {
    union { unsigned int u; float f; } v; v.u = ((unsigned int)h) << 16;
    return v.f;
}

__device__ __forceinline__ void gl16(const void* g, const void* l) {
    __builtin_amdgcn_global_load_lds(
        (const __attribute__((address_space(1))) unsigned int*)g,
        (__attribute__((address_space(3))) unsigned int*)l, 16, 0, 0);
}

// --- x -> padded channels-last bf16 + fused x-GAP partials + halo zeroing ---
__global__ __launch_bounds__(256) void k_xt(const float* __restrict__ x,
                                            unsigned short* __restrict__ xt,
                                            float* __restrict__ gpart) {
    int wg = blockIdx.x + (blockIdx.y << 6);
    int nw = ((wg & 7) << 7) + (wg >> 3);   // XCD swizzle (1024 = 8*128)
    int h = nw & 63, b = nw >> 6;
    int t = threadIdx.x;
    int w = t & 63, c8 = t >> 6;
    unsigned short* xtb = xt + (size_t)b * 66*66*128;
    unsigned short* orow = xtb + (((size_t)(h+1))*66 + (w+1))*128;
    float* gp = gpart + ((size_t)b*64 + h)*128;
    #pragma unroll
    for (int i = 0; i < 4; ++i) {
        int ci0 = i*32 + c8*8;
        float f[8];
        short8v vv;
        #pragma unroll
        for (int j = 0; j < 8; ++j) {
            f[j] = x[(((size_t)b*CIN_ + ci0 + j)*H_ + h)*W_ + w];
            vv[j] = (short)f2bf(f[j]);
        }
        *(short8v*)(orow + ci0) = vv;
        #pragma unroll
        for (int j = 0; j < 8; ++j) {
            float s = f[j];
            s += __shfl_down(s, 32, 64);
            s += __shfl_down(s, 16, 64);
            s += __shfl_down(s, 8, 64);
            s += __shfl_down(s, 4, 64);
            s += __shfl_down(s, 2, 64);
            s += __shfl_down(s, 1, 64);
            f[j] = s;
        }
        if (w == 0) {
            #pragma unroll
            for (int j = 0; j < 8; ++j) gp[ci0 + j] = f[j];
        }
    }
    xtb[(((size_t)(h+1))*66 + (t >> 7)*65)*128 + (t & 127)] = 0;
    if (h == 0 || h == 63) {
        int r = (h == 0) ? 0 : 65;
        unsigned short* rowp = xtb + ((size_t)r*66)*128;
        for (int i = t; i < 1056; i += 256)
            *(short8v*)(rowp + (size_t)i*8) = (short8v){0,0,0,0,0,0,0,0};
    }
}

// --- routing: reduce x-gap partials + MLP + softmax (grid = B) ---
__global__ void k_route(const float* __restrict__ gpart,
                        const float* r1w, const float* r1b,
                        const float* r2w, const float* r2b,
                        const float* r3w, const float* r3b,
                        float* __restrict__ rw) {
    int b = blockIdx.x;
    int t = threadIdx.x;  // 128
    __shared__ float gl_[128];
    float s = 0.f;
    for (int h = 0; h < 64; ++h) s += gpart[((size_t)b*64 + h)*128 + t];
    gl_[t] = s * (1.f/4096.f);
    __syncthreads();
    if (t == 0) {
        float h1[2];
        for (int j = 0; j < 2; ++j) {
            float acc = r1b[j];
            for (int c = 0; c < CIN_; ++c) acc += gl_[c]*r1w[j*CIN_+c];
            h1[j] = fmaxf(acc, 0.f);
        }
        float h2[4];
        for (int e = 0; e < 4; ++e)
            h2[e] = fmaxf(r2b[e] + h1[0]*r2w[e*2] + h1[1]*r2w[e*2+1], 0.f);
        float lg[4], m = -1e30f;
        for (int e = 0; e < 4; ++e) {
            float acc = r3b[e];
            for (int j = 0; j < 4; ++j) acc += h2[j]*r3w[e*4+j];
            lg[e] = acc; m = fmaxf(m, acc);
        }
        float den = 0.f;
        for (int e = 0; e < 4; ++e) { lg[e] = expf(lg[e]-m); den += lg[e]; }
        float inv = 1.f/den;
        for (int e = 0; e < 4; ++e) rw[b*4+e] = lg[e]*inv;
    }
}

// --- combined expert weights -> bf16 [b][tap][co][ci]; blocks >=256 do wsa ---
__global__ __launch_bounds__(256) void k_wcomb(const float* __restrict__ ew,
                                               const float* __restrict__ rw,
                                               unsigned short* __restrict__ wc,
                                               const float* __restrict__ saw,
                                               unsigned short* __restrict__ wsa) {
    int t = threadIdx.x;
    if (blockIdx.x >= COUT_) {
        int i = (blockIdx.x - COUT_)*256 + t;   // 0..16383
        int tap = i >> 8, c = i & 255;
        float v = (tap < 49) ? saw[c*49 + tap] : 0.f;
        wsa[tap*256 + c] = f2bf(v);
        return;
    }
    int co = blockIdx.x;
    __shared__ float ewl[4*1152];
    __shared__ float rwl[64];
    #pragma unroll
    for (int e = 0; e < 4; ++e) {
        const float* src = ew + ((size_t)(e*COUT_ + co))*1152;
        for (int i = t; i < 1152; i += 256) ewl[e*1152 + i] = src[i];
    }
    if (t < 64) rwl[t] = rw[t];
    __syncthreads();
    for (int i = 0; i < 72; ++i) {
        int f = i*256 + t;
        int b = f / 1152;
        int rem = f - b*1152;
        int tap = rem >> 7, ci = rem & 127;
        int lidx = ci*9 + tap;
        float v = rwl[b*4+0]*ewl[0*1152+lidx] + rwl[b*4+1]*ewl[1*1152+lidx]
                + rwl[b*4+2]*ewl[2*1152+lidx] + rwl[b*4+3]*ewl[3*1152+lidx];
        wc[((size_t)(b*9 + tap)*COUT_ + co)*128 + ci] = f2bf(v);
    }
}

// --- MFMA implicit-GEMM conv: 8-phase counted-vmcnt pipeline (m201 template port)
// Block: 256co x 256px (4 rows), 8 waves (2M x 4N), BK=64, 18 K-tiles (tap, ci-half).
// LDS: A/B tiles [kgroup(8)][idx(256)][16B], double-buffered (128 KB), im2col at stage.
// Tile t+2 staged at end of tile t (buffer dead), vmcnt(8) at boundary (never 0).
__global__ __launch_bounds__(512, 2) void k_conv(const unsigned short* __restrict__ xt,
                                                 const unsigned short* __restrict__ wc,
                                                 unsigned short* __restrict__ mixb,
                                                 float* __restrict__ cpart) {
    __shared__ __align__(16) unsigned short lA[32768];   // 64 KB: 2 bufs x [8 kg][256 co][16B]
    __shared__ __align__(16) unsigned short lB[32768];   // 64 KB: 2 bufs x [8 kg][256 px][16B]
    __shared__ float gsl[4][256];                        // 4 KB
    int wg = blockIdx.x;
    int nw = ((wg & 7) << 5) | (wg >> 3);   // XCD swizzle (256 = 8*32)
    int pxt = nw & 15;
    int bb  = nw >> 4;
    int tid = threadIdx.x;
    int wv = tid >> 6, lane = tid & 63;
    int lr = lane & 15, kq = lane >> 4;
    int wm = wv >> 2, wn = wv & 3;

    const unsigned short* xtb = xt + (size_t)bb * 66*66*128;
    const unsigned short* wcb = wc + (size_t)bb * 9*256*128;

    int aidx = (wv & 3)*64 + lane;            // A-staging co index per lane
    int hrow = pxt*4 + (wv & 3);              // B-staging output row per wave

    auto STAGE = [&](int tt) {
        int buf = tt & 1;
        int tap = tt >> 1, cih = (tt & 1) * 64;
        int dh = tap / 3, dw = tap - dh*3;
        const unsigned short* asrc = wcb + ((size_t)tap*256 + aidx)*128 + cih;
        const unsigned short* bsrc = xtb + (((size_t)(hrow + dh))*66 + lane + dw)*128 + cih;
        #pragma unroll
        for (int q = 0; q < 4; ++q) {
            int kg = q*2 + (wv >> 2);
            gl16(asrc + kg*8, (char*)lA + buf*32768 + q*8192 + wv*1024);
            gl16(bsrc + kg*8, (char*)lB + buf*32768 + q*8192 + wv*1024);
        }
    };

    f32x4 acc[8][4];
    #pragma unroll
    for (int m = 0; m < 8; ++m)
        #pragma unroll
        for (int n = 0; n < 4; ++n) acc[m][n] = (f32x4){0.f,0.f,0.f,0.f};

    // prologue: stage tiles 0,1; wait tile 0 (8 of 16 outstanding)
    STAGE(0);
    STAGE(1);
    asm volatile("s_waitcnt vmcnt(8)" ::: "memory");
    __builtin_amdgcn_s_barrier();

    for (int t = 0; t < 18; ++t) {
        int buf = t & 1;
        const char* pa = (const char*)lA + buf*32768 + kq*4096 + (wm*128 + lr)*16;
        const char* pb = (const char*)lB + buf*32768 + kq*4096 + (wn*64 + lr)*16;
        short8v a[4][2], b0[2][2], b1[2][2];

        // phase 0: A m0-3 + B n0-1; MFMA m0-3 x n0-1
        #pragma unroll
        for (int m = 0; m < 4; ++m) {
            a[m][0] = *(const short8v*)(pa + m*256);
            a[m][1] = *(const short8v*)(pa + 16384 + m*256);
        }
        #pragma unroll
        for (int n = 0; n < 2; ++n) {
            b0[n][0] = *(const short8v*)(pb + n*256);
            b0[n][1] = *(const short8v*)(pb + 16384 + n*256);
        }
        __builtin_amdgcn_s_barrier();
        __builtin_amdgcn_s_setprio(1);
        #pragma unroll
        for (int m = 0; m < 4; ++m)
            #pragma unroll
            for (int n = 0; n < 2; ++n)
                #pragma unroll
                for (int ks = 0; ks < 2; ++ks)
                    acc[m][n] = __builtin_amdgcn_mfma_f32_16x16x32_bf16(a[m][ks], b0[n][ks], acc[m][n], 0, 0, 0);
        __builtin_amdgcn_s_setprio(0);
        __builtin_amdgcn_s_barrier();

        // phase 1: B n2-3; MFMA m0-3 x n2-3
        #pragma unroll
        for (int n = 0; n < 2; ++n) {
            b1[n][0] = *(const short8v*)(pb + (2+n)*256);
            b1[n][1] = *(const short8v*)(pb + 16384 + (2+n)*256);
        }
        __builtin_amdgcn_s_barrier();
        __builtin_amdgcn_s_setprio(1);
        #pragma unroll
        for (int m = 0; m < 4; ++m)
            #pragma unroll
            for (int n = 0; n < 2; ++n)
                #pragma unroll
                for (int ks = 0; ks < 2; ++ks)
                    acc[m][2+n] = __builtin_amdgcn_mfma_f32_16x16x32_bf16(a[m][ks], b1[n][ks], acc[m][2+n], 0, 0, 0);
        __builtin_amdgcn_s_setprio(0);
        __builtin_amdgcn_s_barrier();

        // phase 2: A m4-7; MFMA m4-7 x n0-1
        #pragma unroll
        for (int m = 0; m < 4; ++m) {
            a[m][0] = *(const short8v*)(pa + (4+m)*256);
            a[m][1] = *(const short8v*)(pa + 16384 + (4+m)*256);
        }
        __builtin_amdgcn_s_barrier();
        __builtin_amdgcn_s_setprio(1);
        #pragma unroll
        for (int m = 0; m < 4; ++m)
            #pragma unroll
            for (int n = 0; n < 2; ++n)
                #pragma unroll
                for (int ks = 0; ks < 2; ++ks)
                    acc[4+m][n] = __builtin_amdgcn_mfma_f32_16x16x32_bf16(a[m][ks], b0[n][ks], acc[4+m][n], 0, 0, 0);
        __builtin_amdgcn_s_setprio(0);
        __builtin_amdgcn_s_barrier();

        // phase 3: MFMA m4-7 x n2-3
        __builtin_amdgcn_s_barrier();
        __builtin_amdgcn_s_setprio(1);
        #pragma unroll
        for (int m = 0; m < 4; ++m)
            #pragma unroll
            for (int n = 0; n < 2; ++n)
                #pragma unroll
                for (int ks = 0; ks < 2; ++ks)
                    acc[4+m][2+n] = __builtin_amdgcn_mfma_f32_16x16x32_bf16(a[m][ks], b1[n][ks], acc[4+m][2+n], 0, 0, 0);
        __builtin_amdgcn_s_setprio(0);
        __builtin_amdgcn_s_barrier();

        // tile boundary: stage t+2 into buf (dead), counted vmcnt
        __builtin_amdgcn_sched_barrier(0);
        if (t < 16) {
            STAGE(t + 2);
            asm volatile("s_waitcnt vmcnt(8)" ::: "memory");
        } else {
            asm volatile("s_waitcnt vmcnt(0)" ::: "memory");
        }
        __builtin_amdgcn_s_barrier();
    }

    // C write (bf16 mix): co = wm*128 + m*16 + kq*4 + r; px = pxt*256 + wn*64 + n*16 + lr
    unsigned short* ob = mixb + ((size_t)bb*COUT_ + wm*128)*HW_ + pxt*256 + wn*64;
    #pragma unroll
    for (int m = 0; m < 8; ++m)
        #pragma unroll
        for (int n = 0; n < 4; ++n) {
            f32x4 v = acc[m][n];
            #pragma unroll
            for (int r = 0; r < 4; ++r)
                ob[(size_t)(m*16 + kq*4 + r)*HW_ + n*16 + lr] = f2bf(v[r]);
        }

    // fused GAP partials: sum over n-frags + lr lanes, cross-wn via gsl
    float gp[8][4];
    #pragma unroll
    for (int m = 0; m < 8; ++m)
        #pragma unroll
        for (int r = 0; r < 4; ++r) {
            float s = acc[m][0][r] + acc[m][1][r] + acc[m][2][r] + acc[m][3][r];
            #pragma unroll
            for (int o = 8; o > 0; o >>= 1) s += __shfl_down(s, o, 64);
            gp[m][r] = s;
        }
    if (lr == 0) {
        #pragma unroll
        for (int m = 0; m < 8; ++m)
            #pragma unroll
            for (int r = 0; r < 4; ++r)
                gsl[wn][wm*128 + m*16 + kq*4 + r] = gp[m][r];
    }
    __syncthreads();
    if (tid < 256) {
        float s = gsl[0][tid] + gsl[1][tid] + gsl[2][tid] + gsl[3][tid];
        cpart[((size_t)bb*16 + pxt)*COUT_ + tid] = s;
    }
}

// --- SA tap-contraction GEMM + XCD swizzle; u output bf16 ---
__global__ __launch_bounds__(256) void k_sa_gemm(const unsigned short* __restrict__ mixb,
                                                 const unsigned short* __restrict__ wsa,
                                                 unsigned short* __restrict__ u) {
    __shared__ unsigned short wl[16384];
    __shared__ unsigned short bt[16384];
    int wg = blockIdx.x + (blockIdx.y << 6);
    int nw = ((wg & 7) << 7) + (wg >> 3);   // 1024 = 8*128
    int pxt = nw & 63;
    int b   = nw >> 6;
    int t = threadIdx.x, wv = t >> 6, lane = t & 63;
    int lr = lane & 15, kq = lane >> 4;
    int px0 = pxt * 64;

    #pragma unroll
    for (int k = 0; k < 8; ++k) {
        int s = t + k*256;               // 0..2047
        int row = s >> 5, cs = s & 31;
        short8v v = *(const short8v*)(wsa + row*256 + cs*8);
        int off = row*512 + ((cs*16) ^ ((row & 7) << 4));
        *(short8v*)((char*)wl + off) = v;
    }
    {
        int px = lane;
        const unsigned short* mb = mixb + (size_t)b*COUT_*HW_ + px0 + px;
        #pragma unroll
        for (int c8 = 0; c8 < 8; ++c8) {
            int cb = wv*64 + c8*8;
            short8v v;
            #pragma unroll
            for (int j = 0; j < 8; ++j)
                v[j] = (short)mb[(size_t)(cb + j)*HW_];
            int off = px*512 + ((cb*2) ^ ((px & 7) << 4));
            *(short8v*)((char*)bt + off) = v;
        }
    }
    __syncthreads();

    f32x4 acc[4];
    #pragma unroll
    for (int n = 0; n < 4; ++n) acc[n] = (f32x4){0.f,0.f,0.f,0.f};

    #pragma unroll
    for (int ks = 0; ks < 8; ++ks) {
        int ci0 = ks*32;
        int arow = wv*16 + lr;
        short8v a = *(const short8v*)((const char*)wl +
                        arow*512 + (((ci0 + kq*8)*2) ^ ((arow & 7) << 4)));
        #pragma unroll
        for (int n = 0; n < 4; ++n) {
            int prow = n*16 + lr;
            short8v bv = *(const short8v*)((const char*)bt +
                            prow*512 + (((ci0 + kq*8)*2) ^ ((prow & 7) << 4)));
            acc[n] = __builtin_amdgcn_mfma_f32_16x16x32_bf16(a, bv, acc[n], 0, 0, 0);
        }
    }

    unsigned short* ub = u + (size_t)b*64*HW_;
    #pragma unroll
    for (int n = 0; n < 4; ++n)
        #pragma unroll
        for (int r = 0; r < 4; ++r)
            ub[(size_t)(wv*16 + kq*4 + r)*HW_ + px0 + n*16 + lr] = f2bf(acc[n][r]);
}

// --- SA tap-shift reduce + sigmoid; hg==0 blocks also compute channel attention ---
__global__ void k_sared_ca(const unsigned short* __restrict__ u, const float* __restrict__ sab,
                           float* __restrict__ sa,
                           const float* __restrict__ cpart,
                           const float* __restrict__ ca1w, const float* __restrict__ ca1b,
                           const float* __restrict__ ca2w, const float* __restrict__ ca2b,
                           float* __restrict__ ca) {
    int wg = blockIdx.x + (blockIdx.y << 4);
    int nw = ((wg & 7) << 5) + (wg >> 3);   // 256 = 8*32
    int hg = nw & 15;
    int b  = nw >> 4;
    int t = threadIdx.x;
    {
        int h = hg * 4 + (t >> 6);
        int w = t & 63;
        float s = sab[0];
        const unsigned short* ub = u + (size_t)b*64*HW_;
        #pragma unroll
        for (int dh = 0; dh < 7; ++dh) {
            int hh = h + dh - 3;
            if (hh < 0 || hh >= H_) continue;
            #pragma unroll
            for (int dw = 0; dw < 7; ++dw) {
                int ww = w + dw - 3;
                if (ww < 0 || ww >= W_) continue;
                s += bf2f(ub[(size_t)(dh*7 + dw)*HW_ + hh*W_ + ww]);
            }
        }
        sa[(size_t)b*HW_ + h*W_ + w] = 1.f/(1.f + expf(-s));
    }
    if (hg == 0) {
        __shared__ float pfull[256];
        __shared__ float h1[64];
        float s0 = 0.f;
        for (int h = 0; h < 16; ++h) s0 += cpart[((size_t)b*16 + h)*COUT_ + t];
        pfull[t] = s0 * (1.f/(float)HW_);
        __syncthreads();
        if (t < 64) {
            float s = ca1b[t];
            for (int c = 0; c < COUT_; ++c) s += pfull[c] * ca1w[t*COUT_ + c];
            h1[t] = fmaxf(s, 0.f);
        }
        __syncthreads();
        float s2 = ca2b[t];
        for (int j = 0; j < 64; ++j) s2 += h1[j] * ca2w[t*64 + j];
        ca[b*COUT_ + t] = 1.f/(1.f + expf(-s2));
    }
}

// --- BN stats + finalize: grid = 256 (one block per channel) ---
__global__ void k_statsfin(const unsigned short* __restrict__ mixb,
                           const float* __restrict__ ca, const float* __restrict__ sa,
                           const float* __restrict__ gamma, const float* __restrict__ beta,
                           float* __restrict__ scale, float* __restrict__ shift) {
    int c = blockIdx.x;
    int t = threadIdx.x;
    float s = 0.f, sq = 0.f;
    for (int b = 0; b < B_; ++b) {
        float cav = ca[b*COUT_ + c];
        const unsigned short* pl = mixb + ((size_t)b*COUT_ + c) * HW_;
        const float* sab = sa + (size_t)b * HW_;
        for (int i = t; i < HW_/8; i += 256) {
            short8v v = ((const short8v*)pl)[i];
            float4 w0 = ((const float4*)sab)[2*i];
            float4 w1 = ((const float4*)sab)[2*i+1];
            float f0 = bf2f((unsigned short)v[0])*cav*w0.x;
            float f1 = bf2f((unsigned short)v[1])*cav*w0.y;
            float f2 = bf2f((unsigned short)v[2])*cav*w0.z;
            float f3 = bf2f((unsigned short)v[3])*cav*w0.w;
            float f4 = bf2f((unsigned short)v[4])*cav*w1.x;
            float f5 = bf2f((unsigned short)v[5])*cav*w1.y;
            float f6 = bf2f((unsigned short)v[6])*cav*w1.z;
            float f7 = bf2f((unsigned short)v[7])*cav*w1.w;
            s  += f0+f1+f2+f3+f4+f5+f6+f7;
            sq += f0*f0+f1*f1+f2*f2+f3*f3+f4*f4+f5*f5+f6*f6+f7*f7;
        }
    }
    for (int o = 32; o > 0; o >>= 1) { s += __shfl_down(s,o,64); sq += __shfl_down(sq,o,64); }
    __shared__ float ls[8];
    int wid = t >> 6, lane = t & 63;
    if (lane == 0) { ls[wid] = s; ls[4+wid] = sq; }
    __syncthreads();
    if (t == 0) {
        float ts = ls[0]+ls[1]+ls[2]+ls[3];
        float tq = ls[4]+ls[5]+ls[6]+ls[7];
        float n = (float)(B_*HW_);
        float mean = ts/n;
        float var = tq/n - mean*mean;
        float sc = gamma[c] * rsqrtf(var + 1e-5f);
        scale[c] = sc;
        shift[c] = beta[c] - mean*sc;
    }
}

// --- recompute mix*ca*sa from bf16 mix, BN + ReLU -> fp32 d_out (XCD swizzle) ---
__global__ void k_bnapply(const unsigned short* __restrict__ mixb, float* __restrict__ out,
                          const float* __restrict__ ca, const float* __restrict__ sa,
                          const float* __restrict__ scale, const float* __restrict__ shift) {
    int wg = blockIdx.x;
    int nw = ((wg & 7) << 10) + (wg >> 3);   // 8192 = 8*1024
    size_t i = (size_t)nw * 256 + threadIdx.x;   // short8 idx
    int c = (int)((i >> 9) & 255);
    int b = (int)(i >> 17);
    int px8 = (int)(i & 511);
    float cav = ca[b*COUT_ + c];
    float sc = scale[c], sh = shift[c];
    short8v v = ((const short8v*)mixb)[i];
    const float4* sp = (const float4*)(sa + (size_t)b*HW_) + (size_t)px8*2;
    float4 w0 = sp[0], w1 = sp[1];
    float4 o0, o1;
    o0.x = fmaxf(fmaf(bf2f((unsigned short)v[0])*cav*w0.x, sc, sh), 0.f);
    o0.y = fmaxf(fmaf(bf2f((unsigned short)v[1])*cav*w0.y, sc, sh), 0.f);
    o0.z = fmaxf(fmaf(bf2f((unsigned short)v[2])*cav*w0.z, sc, sh), 0.f);
    o0.w = fmaxf(fmaf(bf2f((unsigned short)v[3])*cav*w0.w, sc, sh), 0.f);
    o1.x = fmaxf(fmaf(bf2f((unsigned short)v[4])*cav*w1.x, sc, sh), 0.f);
    o1.y = fmaxf(fmaf(bf2f((unsigned short)v[5])*cav*w1.y, sc, sh), 0.f);
    o1.z = fmaxf(fmaf(bf2f((unsigned short)v[6])*cav*w1.z, sc, sh), 0.f);
    o1.w = fmaxf(fmaf(bf2f((unsigned short)v[7])*cav*w1.w, sc, sh), 0.f);
    ((float4*)out)[i*2]   = o0;
    ((float4*)out)[i*2+1] = o1;
}

extern "C" void kernel_launch(void* const* d_in, const int* in_sizes, int n_in,
                              void* d_out, int out_size, void* d_ws, size_t ws_size,
                              hipStream_t stream) {
    const float* x    = (const float*)d_in[0];
    const float* ew   = (const float*)d_in[1];
    const float* r1w  = (const float*)d_in[2];
    const float* r1b  = (const float*)d_in[3];
    const float* r2w  = (const float*)d_in[4];
    const float* r2b  = (const float*)d_in[5];
    const float* r3w  = (const float*)d_in[6];
    const float* r3b  = (const float*)d_in[7];
    const float* ca1w = (const float*)d_in[8];
    const float* ca1b = (const float*)d_in[9];
    const float* ca2w = (const float*)d_in[10];
    const float* ca2b = (const float*)d_in[11];
    const float* saw  = (const float*)d_in[12];
    const float* sab  = (const float*)d_in[13];
    const float* gm   = (const float*)d_in[14];
    const float* bt   = (const float*)d_in[15];
    float* out = (float*)d_out;
    float* ws  = (float*)d_ws;
    unsigned short* wcb  = (unsigned short*)(ws + WS_WCB_F);
    unsigned short* xt   = (unsigned short*)(ws + WS_XT_F);
    unsigned short* wsa  = (unsigned short*)(ws + WS_WSA);
    unsigned short* mixb = (unsigned short*)(ws + WS_MIX_F);
    unsigned short* u    = (unsigned short*)(ws + WS_U_F);  // overlaps xt (dead after conv)

    k_xt<<<dim3(64,16), 256, 0, stream>>>(x, xt, ws+WS_GPX);
    k_route<<<16, 128, 0, stream>>>(ws+WS_GPX, r1w, r1b, r2w, r2b, r3w, r3b, ws+WS_RW);
    k_wcomb<<<320, 256, 0, stream>>>(ew, ws+WS_RW, wcb, saw, wsa);
    k_conv<<<256, 512, 0, stream>>>(xt, wcb, mixb, ws+WS_CP);
    k_sa_gemm<<<dim3(64,16), 256, 0, stream>>>(mixb, wsa, u);
    k_sared_ca<<<dim3(16,16), 256, 0, stream>>>(u, sab, ws+WS_SA, ws+WS_CP,
                                                ca1w, ca1b, ca2w, ca2b, ws+WS_CA);
    k_statsfin<<<256, 256, 0, stream>>>(mixb, ws+WS_CA, ws+WS_SA, gm, bt,
                                        ws+WS_BNSCALE, ws+WS_BNSHIFT);
    k_bnapply<<<8192, 256, 0, stream>>>(mixb, out, ws+WS_CA, ws+WS_SA,
                                        ws+WS_BNSCALE, ws+WS_BNSHIFT);
}

// Round 12
// 136.967 us; speedup vs baseline: 1.4609x; 1.4609x over previous
//
#include <hip/hip_runtime.h>
#include <math.h>

#define B_    16
#define CIN_  128
#define COUT_ 256
#define H_    64
#define W_    64
#define HW_   4096

typedef __attribute__((ext_vector_type(8))) short short8v;
typedef __attribute__((ext_vector_type(4))) float f32x4;

// workspace layout (float offsets)
#define WS_GPX     0          // [16][64][128] = 131072
#define WS_RW      131072     // 64
#define WS_CP      131136     // conv gap partials [16][8][256] = 32768
#define WS_CA      196672     // 4096
#define WS_BNSCALE 208960     // 256
#define WS_BNSHIFT 209216     // 256
#define WS_SA      209472     // 65536
#define WS_WSA     275008     // 16384 bf16 = 8192 floats
#define WS_WCB_F   283200     // bf16 [16][9][256][128] = 4718592 bf16 = 2359296 floats
#define WS_XT_F    2642496    // bf16 [16][66][66][128] = 8921088 bf16 = 4460544 floats
#define WS_U_F     WS_XT_F    // bf16 [16][64][4096] (xt dead after conv)
#define WS_MIX_F   7103040    // bf16 [16][256][4096] = 16777216 bf16 = 8388608 floats

static __device__ __forceinline__ unsigned short f2bf(float f) {
    union { float f; unsigned int u; } v; v.f = f;
    unsigned int u = v.u;
    return (unsigned short)((u + 0x7FFFu + ((u >> 16) & 1u)) >> 16);  // RTNE
}
static __device__ __forceinline__ float bf2f(unsigned short h) {
    union { unsigned int u; float f; } v; v.u = ((unsigned int)h) << 16;
    return v.f;
}

__device__ __forceinline__ void gl16(const void* g, const void* l) {
    __builtin_amdgcn_global_load_lds(
        (const __attribute__((address_space(1))) unsigned int*)g,
        (__attribute__((address_space(3))) unsigned int*)l, 16, 0, 0);
}

// --- x -> padded channels-last bf16 + fused x-GAP partials + halo zeroing ---
__global__ __launch_bounds__(256) void k_xt(const float* __restrict__ x,
                                            unsigned short* __restrict__ xt,
                                            float* __restrict__ gpart) {
    int wg = blockIdx.x + (blockIdx.y << 6);
    int nw = ((wg & 7) << 7) + (wg >> 3);   // XCD swizzle (1024 = 8*128)
    int h = nw & 63, b = nw >> 6;
    int t = threadIdx.x;
    int w = t & 63, c8 = t >> 6;
    unsigned short* xtb = xt + (size_t)b * 66*66*128;
    unsigned short* orow = xtb + (((size_t)(h+1))*66 + (w+1))*128;
    float* gp = gpart + ((size_t)b*64 + h)*128;
    #pragma unroll
    for (int i = 0; i < 4; ++i) {
        int ci0 = i*32 + c8*8;
        float f[8];
        short8v vv;
        #pragma unroll
        for (int j = 0; j < 8; ++j) {
            f[j] = x[(((size_t)b*CIN_ + ci0 + j)*H_ + h)*W_ + w];
            vv[j] = (short)f2bf(f[j]);
        }
        *(short8v*)(orow + ci0) = vv;
        #pragma unroll
        for (int j = 0; j < 8; ++j) {
            float s = f[j];
            s += __shfl_down(s, 32, 64);
            s += __shfl_down(s, 16, 64);
            s += __shfl_down(s, 8, 64);
            s += __shfl_down(s, 4, 64);
            s += __shfl_down(s, 2, 64);
            s += __shfl_down(s, 1, 64);
            f[j] = s;
        }
        if (w == 0) {
            #pragma unroll
            for (int j = 0; j < 8; ++j) gp[ci0 + j] = f[j];
        }
    }
    xtb[(((size_t)(h+1))*66 + (t >> 7)*65)*128 + (t & 127)] = 0;
    if (h == 0 || h == 63) {
        int r = (h == 0) ? 0 : 65;
        unsigned short* rowp = xtb + ((size_t)r*66)*128;
        for (int i = t; i < 1056; i += 256)
            *(short8v*)(rowp + (size_t)i*8) = (short8v){0,0,0,0,0,0,0,0};
    }
}

// --- routing: reduce x-gap partials + MLP + softmax (grid = B) ---
__global__ void k_route(const float* __restrict__ gpart,
                        const float* r1w, const float* r1b,
                        const float* r2w, const float* r2b,
                        const float* r3w, const float* r3b,
                        float* __restrict__ rw) {
    int b = blockIdx.x;
    int t = threadIdx.x;  // 128
    __shared__ float gl_[128];
    float s = 0.f;
    for (int h = 0; h < 64; ++h) s += gpart[((size_t)b*64 + h)*128 + t];
    gl_[t] = s * (1.f/4096.f);
    __syncthreads();
    if (t == 0) {
        float h1[2];
        for (int j = 0; j < 2; ++j) {
            float acc = r1b[j];
            for (int c = 0; c < CIN_; ++c) acc += gl_[c]*r1w[j*CIN_+c];
            h1[j] = fmaxf(acc, 0.f);
        }
        float h2[4];
        for (int e = 0; e < 4; ++e)
            h2[e] = fmaxf(r2b[e] + h1[0]*r2w[e*2] + h1[1]*r2w[e*2+1], 0.f);
        float lg[4], m = -1e30f;
        for (int e = 0; e < 4; ++e) {
            float acc = r3b[e];
            for (int j = 0; j < 4; ++j) acc += h2[j]*r3w[e*4+j];
            lg[e] = acc; m = fmaxf(m, acc);
        }
        float den = 0.f;
        for (int e = 0; e < 4; ++e) { lg[e] = expf(lg[e]-m); den += lg[e]; }
        float inv = 1.f/den;
        for (int e = 0; e < 4; ++e) rw[b*4+e] = lg[e]*inv;
    }
}

// --- combined expert weights -> bf16 [b][tap][co][ci]; blocks >=256 do wsa ---
__global__ __launch_bounds__(256) void k_wcomb(const float* __restrict__ ew,
                                               const float* __restrict__ rw,
                                               unsigned short* __restrict__ wc,
                                               const float* __restrict__ saw,
                                               unsigned short* __restrict__ wsa) {
    int t = threadIdx.x;
    if (blockIdx.x >= COUT_) {
        int i = (blockIdx.x - COUT_)*256 + t;   // 0..16383
        int tap = i >> 8, c = i & 255;
        float v = (tap < 49) ? saw[c*49 + tap] : 0.f;
        wsa[tap*256 + c] = f2bf(v);
        return;
    }
    int co = blockIdx.x;
    __shared__ float ewl[4*1152];
    __shared__ float rwl[64];
    #pragma unroll
    for (int e = 0; e < 4; ++e) {
        const float* src = ew + ((size_t)(e*COUT_ + co))*1152;
        for (int i = t; i < 1152; i += 256) ewl[e*1152 + i] = src[i];
    }
    if (t < 64) rwl[t] = rw[t];
    __syncthreads();
    for (int i = 0; i < 72; ++i) {
        int f = i*256 + t;
        int b = f / 1152;
        int rem = f - b*1152;
        int tap = rem >> 7, ci = rem & 127;
        int lidx = ci*9 + tap;
        float v = rwl[b*4+0]*ewl[0*1152+lidx] + rwl[b*4+1]*ewl[1*1152+lidx]
                + rwl[b*4+2]*ewl[2*1152+lidx] + rwl[b*4+3]*ewl[3*1152+lidx];
        wc[((size_t)(b*9 + tap)*COUT_ + co)*128 + ci] = f2bf(v);
    }
}

// --- MFMA implicit-GEMM conv: 64co x 128px wave tile (2 rows/wave, 8 rows/block)
// wl: [9 tap][4 kq][64 co][16B]; xs: [10 row][4 kq][66 col][16B] (padded to 42 kslots)
// reads/MFMA = 0.375; verified round-10 structure (2-phase family).
__global__ __launch_bounds__(256, 2) void k_conv(const unsigned short* __restrict__ xt,
                                                 const unsigned short* __restrict__ wc,
                                                 unsigned short* __restrict__ mixb,
                                                 float* __restrict__ cpart) {
    __shared__ __align__(16) unsigned short xs[21504];   // 43.0 KB (42*64 slots, 2640 used)
    __shared__ __align__(16) unsigned short wl[18432];   // 36.9 KB
    __shared__ float gsl[4][64];
    int wg = blockIdx.x + (blockIdx.y << 3) + (blockIdx.z << 5);  // 8 ht, 4 cb, 16 b
    int nw = ((wg & 7) << 6) + (wg >> 3);   // XCD swizzle (512 = 8*64)
    int ht = nw & 7;
    int cb = (nw >> 3) & 3;
    int b  = nw >> 5;
    int t  = threadIdx.x;
    int wv = t >> 6, lane = t & 63;
    int lr = lane & 15, kq = lane >> 4;
    int h0 = ht * 8;

    const unsigned short* xtb = xt + (size_t)b * 66*66*128;
    const unsigned short* wcb = wc + (size_t)b * 9*256*128;

    const char* xs_c = (const char*)xs;
    const char* wl_c = (const char*)wl;
    int base_x = wv*8448 + kq*1056 + lr*16;   // + (dh + (n>>2))*4224 + (n&3)*256 + dw*16
    int base_w = kq*1024 + lr*16;             // + tap*4096 + m*256

    f32x4 acc[4][8];
    #pragma unroll
    for (int m = 0; m < 4; ++m)
        #pragma unroll
        for (int n = 0; n < 8; ++n) acc[m][n] = (f32x4){0.f,0.f,0.f,0.f};

    for (int ci0 = 0; ci0 < CIN_; ci0 += 32) {
        __syncthreads();
        // stage xs: 2640 slots (10 rows x 4 kq x 66 cols), source-clamped tail
        for (int j = wv; j < 42; j += 4) {
            int s = j*64 + lane;
            if (s > 2639) s = 2639;
            int row = s / 264;
            int rem = s - row*264;
            int kq2 = rem / 66, col = rem - kq2*66;
            const unsigned short* g = xtb + (((size_t)(h0 + row)*66 + col)*128 + ci0 + kq2*8);
            gl16(g, (const char*)xs + (size_t)j*1024);
        }
        // stage wl: slot s -> tap = s>>8, kq2 = (s>>6)&3, co = s&63
        for (int j = wv; j < 36; j += 4) {
            int s = j*64 + lane;
            int tap = s >> 8, kq2 = (s >> 6) & 3, co = s & 63;
            const unsigned short* g = wcb + (((size_t)tap*COUT_ + cb*64 + co)*128 + ci0 + kq2*8);
            gl16(g, (const char*)wl + (size_t)j*1024);
        }
        asm volatile("s_waitcnt vmcnt(0)" ::: "memory");
        __syncthreads();

        #pragma unroll
        for (int dh = 0; dh < 3; ++dh) {
            #pragma unroll
            for (int dw = 0; dw < 3; ++dw) {
                int tap = dh*3 + dw;
                short8v af[4];
                #pragma unroll
                for (int m = 0; m < 4; ++m)
                    af[m] = *(const short8v*)(wl_c + base_w + tap*4096 + m*256);
                short8v bf[8];
                #pragma unroll
                for (int n = 0; n < 8; ++n)
                    bf[n] = *(const short8v*)(xs_c + base_x +
                               (dh + (n>>2))*4224 + (n&3)*256 + dw*16);
                #pragma unroll
                for (int m = 0; m < 4; ++m)
                    #pragma unroll
                    for (int n = 0; n < 8; ++n)
                        acc[m][n] = __builtin_amdgcn_mfma_f32_16x16x32_bf16(
                            af[m], bf[n], acc[m][n], 0, 0, 0);
            }
        }
    }

    // C write (bf16 mix): wave rows h0 + wv*2 + (n>>2)
    unsigned short* ob = mixb + ((size_t)b*COUT_ + cb*64)*HW_ + (h0 + wv*2)*W_;
    #pragma unroll
    for (int m = 0; m < 4; ++m)
        #pragma unroll
        for (int n = 0; n < 8; ++n) {
            f32x4 v = acc[m][n];
            #pragma unroll
            for (int r = 0; r < 4; ++r)
                ob[(size_t)(m*16 + kq*4 + r)*HW_ + (n>>2)*W_ + (n&3)*16 + lr] = f2bf(v[r]);
        }

    // fused GAP partials: sum over 8 n-frags and 16 lr lanes
    float gp[4][4];
    #pragma unroll
    for (int m = 0; m < 4; ++m)
        #pragma unroll
        for (int r = 0; r < 4; ++r) {
            float s = 0.f;
            #pragma unroll
            for (int n = 0; n < 8; ++n) s += acc[m][n][r];
            gp[m][r] = s;
        }
    #pragma unroll
    for (int o = 8; o > 0; o >>= 1)
        #pragma unroll
        for (int m = 0; m < 4; ++m)
            #pragma unroll
            for (int r = 0; r < 4; ++r)
                gp[m][r] += __shfl_down(gp[m][r], o, 64);
    if ((lane & 15) == 0) {
        #pragma unroll
        for (int m = 0; m < 4; ++m)
            #pragma unroll
            for (int r = 0; r < 4; ++r)
                gsl[wv][m*16 + kq*4 + r] = gp[m][r];
    }
    __syncthreads();
    if (t < 64) {
        float s = gsl[0][t] + gsl[1][t] + gsl[2][t] + gsl[3][t];
        cpart[((size_t)b*8 + ht)*COUT_ + cb*64 + t] = s;
    }
}

// --- SA tap-contraction GEMM + XCD swizzle; u output bf16 ---
__global__ __launch_bounds__(256) void k_sa_gemm(const unsigned short* __restrict__ mixb,
                                                 const unsigned short* __restrict__ wsa,
                                                 unsigned short* __restrict__ u) {
    __shared__ unsigned short wl[16384];
    __shared__ unsigned short bt[16384];
    int wg = blockIdx.x + (blockIdx.y << 6);
    int nw = ((wg & 7) << 7) + (wg >> 3);   // 1024 = 8*128
    int pxt = nw & 63;
    int b   = nw >> 6;
    int t = threadIdx.x, wv = t >> 6, lane = t & 63;
    int lr = lane & 15, kq = lane >> 4;
    int px0 = pxt * 64;

    #pragma unroll
    for (int k = 0; k < 8; ++k) {
        int s = t + k*256;               // 0..2047
        int row = s >> 5, cs = s & 31;
        short8v v = *(const short8v*)(wsa + row*256 + cs*8);
        int off = row*512 + ((cs*16) ^ ((row & 7) << 4));
        *(short8v*)((char*)wl + off) = v;
    }
    {
        int px = lane;
        const unsigned short* mb = mixb + (size_t)b*COUT_*HW_ + px0 + px;
        #pragma unroll
        for (int c8 = 0; c8 < 8; ++c8) {
            int cb = wv*64 + c8*8;
            short8v v;
            #pragma unroll
            for (int j = 0; j < 8; ++j)
                v[j] = (short)mb[(size_t)(cb + j)*HW_];
            int off = px*512 + ((cb*2) ^ ((px & 7) << 4));
            *(short8v*)((char*)bt + off) = v;
        }
    }
    __syncthreads();

    f32x4 acc[4];
    #pragma unroll
    for (int n = 0; n < 4; ++n) acc[n] = (f32x4){0.f,0.f,0.f,0.f};

    #pragma unroll
    for (int ks = 0; ks < 8; ++ks) {
        int ci0 = ks*32;
        int arow = wv*16 + lr;
        short8v a = *(const short8v*)((const char*)wl +
                        arow*512 + (((ci0 + kq*8)*2) ^ ((arow & 7) << 4)));
        #pragma unroll
        for (int n = 0; n < 4; ++n) {
            int prow = n*16 + lr;
            short8v bv = *(const short8v*)((const char*)bt +
                            prow*512 + (((ci0 + kq*8)*2) ^ ((prow & 7) << 4)));
            acc[n] = __builtin_amdgcn_mfma_f32_16x16x32_bf16(a, bv, acc[n], 0, 0, 0);
        }
    }

    unsigned short* ub = u + (size_t)b*64*HW_;
    #pragma unroll
    for (int n = 0; n < 4; ++n)
        #pragma unroll
        for (int r = 0; r < 4; ++r)
            ub[(size_t)(wv*16 + kq*4 + r)*HW_ + px0 + n*16 + lr] = f2bf(acc[n][r]);
}

// --- SA tap-shift reduce + sigmoid; hg==0 blocks also compute channel attention ---
__global__ void k_sared_ca(const unsigned short* __restrict__ u, const float* __restrict__ sab,
                           float* __restrict__ sa,
                           const float* __restrict__ cpart,
                           const float* __restrict__ ca1w, const float* __restrict__ ca1b,
                           const float* __restrict__ ca2w, const float* __restrict__ ca2b,
                           float* __restrict__ ca) {
    int wg = blockIdx.x + (blockIdx.y << 4);
    int nw = ((wg & 7) << 5) + (wg >> 3);   // 256 = 8*32
    int hg = nw & 15;
    int b  = nw >> 4;
    int t = threadIdx.x;
    {
        int h = hg * 4 + (t >> 6);
        int w = t & 63;
        float s = sab[0];
        const unsigned short* ub = u + (size_t)b*64*HW_;
        #pragma unroll
        for (int dh = 0; dh < 7; ++dh) {
            int hh = h + dh - 3;
            if (hh < 0 || hh >= H_) continue;
            #pragma unroll
            for (int dw = 0; dw < 7; ++dw) {
                int ww = w + dw - 3;
                if (ww < 0 || ww >= W_) continue;
                s += bf2f(ub[(size_t)(dh*7 + dw)*HW_ + hh*W_ + ww]);
            }
        }
        sa[(size_t)b*HW_ + h*W_ + w] = 1.f/(1.f + expf(-s));
    }
    if (hg == 0) {
        __shared__ float pfull[256];
        __shared__ float h1[64];
        float s0 = 0.f;
        for (int h = 0; h < 8; ++h) s0 += cpart[((size_t)b*8 + h)*COUT_ + t];
        pfull[t] = s0 * (1.f/(float)HW_);
        __syncthreads();
        if (t < 64) {
            float s = ca1b[t];
            for (int c = 0; c < COUT_; ++c) s += pfull[c] * ca1w[t*COUT_ + c];
            h1[t] = fmaxf(s, 0.f);
        }
        __syncthreads();
        float s2 = ca2b[t];
        for (int j = 0; j < 64; ++j) s2 += h1[j] * ca2w[t*64 + j];
        ca[b*COUT_ + t] = 1.f/(1.f + expf(-s2));
    }
}

// --- BN stats + finalize: grid = 256 (one block per channel) ---
__global__ void k_statsfin(const unsigned short* __restrict__ mixb,
                           const float* __restrict__ ca, const float* __restrict__ sa,
                           const float* __restrict__ gamma, const float* __restrict__ beta,
                           float* __restrict__ scale, float* __restrict__ shift) {
    int c = blockIdx.x;
    int t = threadIdx.x;
    float s = 0.f, sq = 0.f;
    for (int b = 0; b < B_; ++b) {
        float cav = ca[b*COUT_ + c];
        const unsigned short* pl = mixb + ((size_t)b*COUT_ + c) * HW_;
        const float* sab = sa + (size_t)b * HW_;
        for (int i = t; i < HW_/8; i += 256) {
            short8v v = ((const short8v*)pl)[i];
            float4 w0 = ((const float4*)sab)[2*i];
            float4 w1 = ((const float4*)sab)[2*i+1];
            float f0 = bf2f((unsigned short)v[0])*cav*w0.x;
            float f1 = bf2f((unsigned short)v[1])*cav*w0.y;
            float f2 = bf2f((unsigned short)v[2])*cav*w0.z;
            float f3 = bf2f((unsigned short)v[3])*cav*w0.w;
            float f4 = bf2f((unsigned short)v[4])*cav*w1.x;
            float f5 = bf2f((unsigned short)v[5])*cav*w1.y;
            float f6 = bf2f((unsigned short)v[6])*cav*w1.z;
            float f7 = bf2f((unsigned short)v[7])*cav*w1.w;
            s  += f0+f1+f2+f3+f4+f5+f6+f7;
            sq += f0*f0+f1*f1+f2*f2+f3*f3+f4*f4+f5*f5+f6*f6+f7*f7;
        }
    }
    for (int o = 32; o > 0; o >>= 1) { s += __shfl_down(s,o,64); sq += __shfl_down(sq,o,64); }
    __shared__ float ls[8];
    int wid = t >> 6, lane = t & 63;
    if (lane == 0) { ls[wid] = s; ls[4+wid] = sq; }
    __syncthreads();
    if (t == 0) {
        float ts = ls[0]+ls[1]+ls[2]+ls[3];
        float tq = ls[4]+ls[5]+ls[6]+ls[7];
        float n = (float)(B_*HW_);
        float mean = ts/n;
        float var = tq/n - mean*mean;
        float sc = gamma[c] * rsqrtf(var + 1e-5f);
        scale[c] = sc;
        shift[c] = beta[c] - mean*sc;
    }
}

// --- recompute mix*ca*sa from bf16 mix, BN + ReLU -> fp32 d_out (XCD swizzle) ---
__global__ void k_bnapply(const unsigned short* __restrict__ mixb, float* __restrict__ out,
                          const float* __restrict__ ca, const float* __restrict__ sa,
                          const float* __restrict__ scale, const float* __restrict__ shift) {
    int wg = blockIdx.x;
    int nw = ((wg & 7) << 10) + (wg >> 3);   // 8192 = 8*1024
    size_t i = (size_t)nw * 256 + threadIdx.x;   // short8 idx
    int c = (int)((i >> 9) & 255);
    int b = (int)(i >> 17);
    int px8 = (int)(i & 511);
    float cav = ca[b*COUT_ + c];
    float sc = scale[c], sh = shift[c];
    short8v v = ((const short8v*)mixb)[i];
    const float4* sp = (const float4*)(sa + (size_t)b*HW_) + (size_t)px8*2;
    float4 w0 = sp[0], w1 = sp[1];
    float4 o0, o1;
    o0.x = fmaxf(fmaf(bf2f((unsigned short)v[0])*cav*w0.x, sc, sh), 0.f);
    o0.y = fmaxf(fmaf(bf2f((unsigned short)v[1])*cav*w0.y, sc, sh), 0.f);
    o0.z = fmaxf(fmaf(bf2f((unsigned short)v[2])*cav*w0.z, sc, sh), 0.f);
    o0.w = fmaxf(fmaf(bf2f((unsigned short)v[3])*cav*w0.w, sc, sh), 0.f);
    o1.x = fmaxf(fmaf(bf2f((unsigned short)v[4])*cav*w1.x, sc, sh), 0.f);
    o1.y = fmaxf(fmaf(bf2f((unsigned short)v[5])*cav*w1.y, sc, sh), 0.f);
    o1.z = fmaxf(fmaf(bf2f((unsigned short)v[6])*cav*w1.z, sc, sh), 0.f);
    o1.w = fmaxf(fmaf(bf2f((unsigned short)v[7])*cav*w1.w, sc, sh), 0.f);
    ((float4*)out)[i*2]   = o0;
    ((float4*)out)[i*2+1] = o1;
}

extern "C" void kernel_launch(void* const* d_in, const int* in_sizes, int n_in,
                              void* d_out, int out_size, void* d_ws, size_t ws_size,
                              hipStream_t stream) {
    const float* x    = (const float*)d_in[0];
    const float* ew   = (const float*)d_in[1];
    const float* r1w  = (const float*)d_in[2];
    const float* r1b  = (const float*)d_in[3];
    const float* r2w  = (const float*)d_in[4];
    const float* r2b  = (const float*)d_in[5];
    const float* r3w  = (const float*)d_in[6];
    const float* r3b  = (const float*)d_in[7];
    const float* ca1w = (const float*)d_in[8];
    const float* ca1b = (const float*)d_in[9];
    const float* ca2w = (const float*)d_in[10];
    const float* ca2b = (const float*)d_in[11];
    const float* saw  = (const float*)d_in[12];
    const float* sab  = (const float*)d_in[13];
    const float* gm   = (const float*)d_in[14];
    const float* bt   = (const float*)d_in[15];
    float* out = (float*)d_out;
    float* ws  = (float*)d_ws;
    unsigned short* wcb  = (unsigned short*)(ws + WS_WCB_F);
    unsigned short* xt   = (unsigned short*)(ws + WS_XT_F);
    unsigned short* wsa  = (unsigned short*)(ws + WS_WSA);
    unsigned short* mixb = (unsigned short*)(ws + WS_MIX_F);
    unsigned short* u    = (unsigned short*)(ws + WS_U_F);  // overlaps xt (dead after conv)

    k_xt<<<dim3(64,16), 256, 0, stream>>>(x, xt, ws+WS_GPX);
    k_route<<<16, 128, 0, stream>>>(ws+WS_GPX, r1w, r1b, r2w, r2b, r3w, r3b, ws+WS_RW);
    k_wcomb<<<320, 256, 0, stream>>>(ew, ws+WS_RW, wcb, saw, wsa);
    k_conv<<<dim3(8,4,16), 256, 0, stream>>>(xt, wcb, mixb, ws+WS_CP);
    k_sa_gemm<<<dim3(64,16), 256, 0, stream>>>(mixb, wsa, u);
    k_sared_ca<<<dim3(16,16), 256, 0, stream>>>(u, sab, ws+WS_SA, ws+WS_CP,
                                                ca1w, ca1b, ca2w, ca2b, ws+WS_CA);
    k_statsfin<<<256, 256, 0, stream>>>(mixb, ws+WS_CA, ws+WS_SA, gm, bt,
                                        ws+WS_BNSCALE, ws+WS_BNSHIFT);
    k_bnapply<<<8192, 256, 0, stream>>>(mixb, out, ws+WS_CA, ws+WS_SA,
                                        ws+WS_BNSCALE, ws+WS_BNSHIFT);
}